// Round 3
// baseline (1926.611 us; speedup 1.0000x reference)
//
#include <hip/hip_runtime.h>
#include <math.h>

// ---- problem constants (from reference) ----
#define T_TOT  200000
#define EE     500
#define EI     100
#define SUBN   20
#define NCH    40      // 2*SUB
#define HIDN   20
#define BNO    34
#define TM     101     // basis kernel length
#define KPAD   104     // kernel length padded to multiple of 4 (zeros)
#define TNO    50      // history length / half kernel
#define HBNO   18
#define TT1    256     // t-tile for conv2/output kernels
#define EPSF   2e-5f   // sound margin for interval determinations

// padded syn row: [64 zeros][T][256 zeros]
#define PADL   64
#define PADR   256
#define SROW   (PADL + T_TOT + PADR)   // 200320

// conv1 tiling: 128 threads x 2 t per thread
#define C1THR  128
#define C1T    256

// relax tiling
#define RTILE  1024
#define RHALO  256
#define RRND   5

// ======================= setup: assignments, small kernels, basis ============
__global__ void k_setup(const float* __restrict__ Ce, const float* __restrict__ Ci,
                        const float* __restrict__ Wh, const float* __restrict__ Wspk,
                        const float* __restrict__ Tau,
                        int* __restrict__ ae, int* __restrict__ ai,
                        float* __restrict__ hkpos, float* __restrict__ hkneg,
                        float* __restrict__ spkk,
                        double* __restrict__ hkd, double* __restrict__ basisd)
{
    int tid = threadIdx.x;  // block 1024
    if (tid < EE) {
        int a = 0;
        for (int s = 0; s < SUBN; ++s) if (Ce[s * EE + tid] > 0.5f) a = s;
        ae[tid] = a;
    } else if (tid < EE + EI) {
        int e = tid - EE; int a = 0;
        for (int s = 0; s < SUBN; ++s) if (Ci[s * EI + e] > 0.5f) a = s;
        ai[e] = a;
    } else if (tid < 664) {
        // hk_r[j] = hist_kern[TNO - j], j in [1,TNO]; zero-fill rest of 64
        int j = tid - 600;
        double hk = 0.0;
        if (j >= 1 && j <= TNO) {
            int i = TNO - j;
            for (int b = 0; b < HBNO; ++b) {
                double d = (double)i - 3.0 * (double)b;
                hk += (double)Wh[b] * exp(-d * d / 3.0);
            }
        }
        hkd[j] = hk;
        hkpos[j] = (float)fmax(hk, 0.0);
        hkneg[j] = (float)fmin(hk, 0.0);
    } else if (tid < 728) {
        int m = tid - 664; float v = 0.f;
        if (m < TNO) {
            double tau2 = (double)Tau[0] * (double)Tau[0];
            double tt = (double)m / tau2;
            v = (float)(tt * exp(-tt) * (double)Wspk[0] * (double)Wspk[0]);
        }
        spkk[m] = v;
    }
    // Gaussian basis table (fp64), shared by kern1/kern4 construction
    for (int idx = tid; idx < BNO * TM; idx += blockDim.x) {
        int b = idx / TM, k = idx % TM;
        double d = (double)k - 3.0 * (double)b;
        basisd[idx] = exp(-d * d / 3.0);
    }
}

// ======================= build conv kernels from basis =======================
// kern1 layout: [s][k(0..103)][h]  (zeros for k>=101) -> contiguous 160B per (s, k-pair)
__global__ void k_makekern(const float* __restrict__ w1, const float* __restrict__ w4,
                           const double* __restrict__ basisd,
                           float* __restrict__ kern1, float* __restrict__ kern4)
{
    int idx = blockIdx.x * 256 + threadIdx.x;
    if (idx < NCH * KPAD * HIDN) {
        int h = idx % HIDN;
        int k = (idx / HIDN) % KPAD;
        int s = idx / (HIDN * KPAD);
        double acc = 0.0;
        if (k < TM) {
            const float* wp = w1 + (h * NCH + s) * BNO;
            for (int b = 0; b < BNO; ++b) acc += (double)wp[b] * basisd[b * TM + k];
        }
        kern1[idx] = (float)acc;
    } else {
        int j = idx - NCH * KPAD * HIDN;
        if (j < HIDN * TM) {
            int h = j % HIDN, k = j / HIDN;
            double acc = 0.0;
            for (int b = 0; b < BNO; ++b) acc += (double)w4[h * BNO + b] * basisd[b * TM + k];
            kern4[k * HIDN + h] = (float)acc;           // [k][h] layout
        }
    }
}

// ======================= synapse -> subunit routing ==========================
__global__ __launch_bounds__(256) void k_route(const float* __restrict__ Se,
                                               const float* __restrict__ Si,
                                               const int* __restrict__ ae,
                                               const int* __restrict__ ai,
                                               float* __restrict__ syn)
{
    __shared__ float acc[NCH * 64];
    __shared__ int sae[EE];
    __shared__ int sai[EI];
    int tid = threadIdx.x;
    for (int i = tid; i < NCH * 64; i += 256) acc[i] = 0.f;
    for (int i = tid; i < EE; i += 256) sae[i] = ae[i];
    for (int i = tid; i < EI; i += 256) sai[i] = ai[i];
    __syncthreads();
    int t0 = blockIdx.x * 64;              // T divisible by 64
    int lane = tid & 63, grp = tid >> 6;
    for (int ec = 0; ec < 8; ++ec) {
        int e = ec * 64 + lane;
        if (e < EE) {
            int a = sae[e];
            for (int ts = grp; ts < 64; ts += 4) {
                float v = Se[(size_t)(t0 + ts) * EE + e];   // coalesced across lanes
                if (v != 0.f) atomicAdd(&acc[a * 64 + ts], v);
            }
        }
    }
    for (int ec = 0; ec < 2; ++ec) {
        int e = ec * 64 + lane;
        if (e < EI) {
            int a = sai[e] + SUBN;
            for (int ts = grp; ts < 64; ts += 4) {
                float v = Si[(size_t)(t0 + ts) * EI + e];
                if (v != 0.f) atomicAdd(&acc[a * 64 + ts], v);
            }
        }
    }
    __syncthreads();
    for (int i = tid; i < NCH * 64; i += 256) {
        int s = i >> 6, ts = i & 63;
        syn[(size_t)s * SROW + PADL + t0 + ts] = acc[i];
    }
}

// ======================= conv1 (40ch -> 20ch, K=101) + leaky_relu ============
// No LDS. 2 t per thread, rolling 4-float register window from global (L1-hit),
// kernel coefficients streamed as block-uniform scalar loads, 80 FMA / group.
__global__ __launch_bounds__(C1THR, 4) void k_conv1(const float* __restrict__ syn,
                                                    const float* __restrict__ kern1,
                                                    float* __restrict__ out1)
{
    int tid = threadIdx.x;
    int t0 = blockIdx.x * C1T;
    int tA = t0 + 2 * tid;                 // thread's two outputs: tA, tA+1
    float accA[HIDN], accB[HIDN];
#pragma unroll
    for (int h = 0; h < HIDN; ++h) { accA[h] = 0.f; accB[h] = 0.f; }

    const float* P = syn + (PADL - TNO) + t0 + 2 * tid;   // row 0, x-offset base
    for (int s = 0; s < NCH; ++s, P += SROW) {
        float2 wa = *(const float2*)(P);
        float2 wb = *(const float2*)(P + 2);
        float w0 = wa.x, w1 = wa.y, w2 = wb.x, w3 = wb.y;
        const float* kp = kern1 + s * (KPAD * HIDN);
        for (int g = 0; g < KPAD / 2; ++g) {
            // prefetch next window pair (independent of FMAs below)
            float2 wn = *(const float2*)(P + 2 * g + 4);
            // batch the 40 block-uniform coefficient loads (k=2g, 2g+1)
            float c0[HIDN], c1[HIDN];
#pragma unroll
            for (int h = 0; h < HIDN; ++h) {
                c0[h] = kp[g * 2 * HIDN + h];
                c1[h] = kp[g * 2 * HIDN + HIDN + h];
            }
#pragma unroll
            for (int h = 0; h < HIDN; ++h) {
                accA[h] = fmaf(c0[h], w0, accA[h]);
                accB[h] = fmaf(c0[h], w1, accB[h]);
                accA[h] = fmaf(c1[h], w1, accA[h]);
                accB[h] = fmaf(c1[h], w2, accB[h]);
            }
            w0 = w2; w1 = w3; w2 = wn.x; w3 = wn.y;
        }
    }
    if (tA < T_TOT) {
#pragma unroll
        for (int h = 0; h < HIDN; ++h) {
            float oa = accA[h], ob = accB[h];
            float2 st;
            st.x = (oa > 0.f) ? oa : 0.01f * oa;
            st.y = (ob > 0.f) ? ob : 0.01f * ob;
            *(float2*)(out1 + (size_t)h * T_TOT + tA) = st;
        }
    }
}

// ======================= conv2 (fp64 acc) + logit threshold ==================
__global__ __launch_bounds__(256) void k_conv2(const float* __restrict__ out1,
                                               const float* __restrict__ kern4,
                                               const float* __restrict__ Theta,
                                               const float* __restrict__ u,
                                               double* __restrict__ xd,
                                               double* __restrict__ thrd,
                                               float* __restrict__ thr32)
{
    __shared__ float s1[HIDN * (TT1 + 100)];    // 28,480 B
    int tid = threadIdx.x;
    int t0 = blockIdx.x * TT1;
    for (int i = tid; i < HIDN * (TT1 + 100); i += 256) {
        int h = i / (TT1 + 100), x = i % (TT1 + 100);
        int g = t0 + x - TNO;
        s1[i] = (g >= 0 && g < T_TOT) ? out1[(size_t)h * T_TOT + g] : 0.f;
    }
    __syncthreads();
    int t = t0 + tid;
    if (t >= T_TOT) return;
    double acc = 0.0;
    for (int k = 0; k < TM; ++k) {
        const float* kp = kern4 + k * HIDN;
#pragma unroll
        for (int h = 0; h < HIDN; ++h)
            acc = fma((double)s1[h * (TT1 + 100) + tid + k], (double)kp[h], acc);
    }
    double x = acc + (double)Theta[0];
    double uu = (double)u[t];
    // spike  <=>  u < sigmoid(x + a)  <=>  a > logit(u) - x
    double th = (log(uu) - log1p(-uu)) - x;     // u==0 -> -inf -> always spike (correct)
    xd[t] = x; thrd[t] = th; thr32[t] = (float)th;
}

// ======================= interval state init + syn pad zero ==================
__global__ void k_init(float* __restrict__ blo, float* __restrict__ bhi,
                       int* __restrict__ dirty, float* __restrict__ syn)
{
    int i = blockIdx.x * 256 + threadIdx.x;
    if (i < T_TOT + 64) {
        blo[i] = 0.f;                                        // index = t + TNO
        bhi[i] = (i >= TNO && i < T_TOT + TNO) ? 1.f : 0.f;  // unknown = (0,1)
    }
    if (i < 256) dirty[i] = 0;
    if (i < NCH * (PADL + PADR)) {
        int r = i / (PADL + PADR), c = i % (PADL + PADR);
        int off = (c < PADL) ? c : (PADL + T_TOT + (c - PADL));
        syn[(size_t)r * SROW + off] = 0.f;
    }
}

// ======================= sound interval relaxation: 5 in-LDS rounds ==========
// Monotone in-place updates (lo only rises, hi only falls) -> racy reads are
// still sound intervals; __syncthreads between rounds gives Jacobi progress.
__global__ __launch_bounds__(256) void k_relax(const float* __restrict__ thr32,
                                               const float* __restrict__ hkpos,
                                               const float* __restrict__ hkneg,
                                               float* __restrict__ blo,
                                               float* __restrict__ bhi)
{
    __shared__ float slo[RTILE + RHALO], shi[RTILE + RHALO];
    __shared__ float sth[RTILE + RHALO];
    __shared__ float shp[64], shn[64];
    int tid = threadIdx.x;
    int t0 = blockIdx.x * RTILE;
    for (int i = tid; i < RTILE + RHALO; i += 256) {
        int t = t0 - RHALO + i;
        int g = t + TNO;
        bool ok = (g >= 0 && g < T_TOT + 64);
        slo[i] = ok ? blo[g] : 0.f;
        shi[i] = ok ? bhi[g] : 0.f;
        sth[i] = (t >= 0 && t < T_TOT) ? thr32[t] : 0.f;
    }
    if (tid < 64) { shp[tid] = hkpos[tid]; shn[tid] = hkneg[tid]; }
    __syncthreads();
    for (int r = 0; r < RRND; ++r) {
        for (int i = tid; i < RTILE + RHALO; i += 256) {
            if (i < TNO) continue;                   // needs 50 left neighbors in LDS
            float l = slo[i], h = shi[i];
            if (l == h) continue;
            float lo = 0.f, hi = 0.f;
            for (int j = 1; j <= TNO; ++j) {
                float bl = slo[i - j], bh = shi[i - j];
                float hp = shp[j], hn = shn[j];
                lo = fmaf(hp, bl, lo); lo = fmaf(hn, bh, lo);
                hi = fmaf(hp, bh, hi); hi = fmaf(hn, bl, hi);
            }
            float th = sth[i];
            if (lo > th + EPSF)      slo[i] = 1.f;   // determined spike
            else if (hi < th - EPSF) shi[i] = 0.f;   // determined no-spike
        }
        __syncthreads();
    }
    for (int i = tid; i < RTILE; i += 256) {         // write back interior only
        int t = t0 + i;
        if (t < T_TOT) {
            blo[t + TNO] = slo[RHALO + i];
            bhi[t + TNO] = shi[RHALO + i];
        }
    }
}

// ======================= per-tile dirty counts ===============================
__global__ __launch_bounds__(1024) void k_mark(const float* __restrict__ blo,
                                               const float* __restrict__ bhi,
                                               int* __restrict__ dirty)
{
    int t = blockIdx.x * 1024 + threadIdx.x;
    int unk = (t < T_TOT) && (blo[t + TNO] != bhi[t + TNO]);
    int c = __syncthreads_count(unk);
    if (threadIdx.x == 0) dirty[blockIdx.x] = c;
}

// ======================= exact sequential cleanup (guarantee) ================
__global__ __launch_bounds__(1024) void k_cleanup(const double* __restrict__ thrd,
                                                  const double* __restrict__ hkd,
                                                  const int* __restrict__ dirty,
                                                  float* __restrict__ blo,
                                                  float* __restrict__ bhi)
{
    __shared__ float sb[64 + 1024];
    __shared__ double shk[64];
    __shared__ int sd[256];
    int tid = threadIdx.x;
    if (tid < 64) shk[tid] = (tid >= 1 && tid <= TNO) ? hkd[tid] : 0.0;
    const int NT = (T_TOT + 1023) / 1024;            // 196
    if (tid < NT) sd[tid] = dirty[tid];
    __syncthreads();
    for (int tile = 0; tile < NT; ++tile) {
        if (sd[tile] == 0) continue;                 // uniform branch, no barrier
        if (tid < 64) {
            int tp = tile * 1024 - 64 + tid;         // tail bits (already final)
            sb[tid] = (tp >= 0) ? blo[tp + TNO] : 0.f;
        }
        int t = tile * 1024 + tid;
        float v = 0.f;
        if (t < T_TOT) {
            float l = blo[t + TNO], h = bhi[t + TNO];
            v = (l == h) ? l : -1.f;                 // -1 marks unknown
        }
        sb[64 + tid] = v;
        __syncthreads();
        if (tid == 0) {
            for (int i = 0; i < 1024; ++i) {
                if (sb[64 + i] < 0.f) {
                    double a = 0.0;
                    for (int j = 1; j <= TNO; ++j) a += shk[j] * (double)sb[64 + i - j];
                    int tt = tile * 1024 + i;
                    float s = (a > thrd[tt]) ? 1.f : 0.f;
                    sb[64 + i] = s; blo[tt + TNO] = s; bhi[tt + TNO] = s;
                }
            }
            __threadfence_block();
        }
        __syncthreads();
    }
}

// ======================= outputs: spk_filt + prob_out ========================
__global__ __launch_bounds__(256) void k_out(const float* __restrict__ blo,
                                             const float* __restrict__ spkk,
                                             const double* __restrict__ hkd,
                                             const double* __restrict__ xd,
                                             float* __restrict__ outp)
{
    __shared__ float sb[TT1 + 64];
    __shared__ float ssp[64];
    __shared__ double shk[64];
    int tid = threadIdx.x;
    int t0 = blockIdx.x * TT1;
    for (int i = tid; i < TT1 + TNO; i += 256) {
        int g = t0 + i;
        sb[i] = (g < T_TOT + 64) ? blo[g] : 0.f;
    }
    if (tid < 64) { ssp[tid] = spkk[tid]; shk[tid] = hkd[tid]; }
    __syncthreads();
    int t = t0 + tid;
    if (t >= T_TOT) return;
    float filt = 0.f;
    double a = 0.0;
    for (int m = 1; m <= TNO; ++m) {
        float b = sb[tid + TNO - m];             // spk[t-m]
        filt = fmaf(b, ssp[m - 1], filt);        // spk_kern[m-1]
        a += shk[m] * (double)b;                 // hist feedback (exact)
    }
    double p = 1.0 / (1.0 + exp(-(xd[t] + a)));
    outp[t] = filt;
    outp[T_TOT + t] = (float)p;
}

// ======================= launcher ===========================================
extern "C" void kernel_launch(void* const* d_in, const int* in_sizes, int n_in,
                              void* d_out, int out_size, void* d_ws, size_t ws_size,
                              hipStream_t stream)
{
    (void)in_sizes; (void)n_in; (void)out_size; (void)ws_size;
    const float* Se = (const float*)d_in[0];
    const float* Si = (const float*)d_in[1];
    const float* Ce = (const float*)d_in[2];
    const float* Ci = (const float*)d_in[3];
    const float* w1 = (const float*)d_in[4];
    const float* w4 = (const float*)d_in[5];
    const float* Wh = (const float*)d_in[6];
    const float* Th = (const float*)d_in[7];
    const float* Ws = (const float*)d_in[8];
    const float* Ta = (const float*)d_in[9];
    const float* u  = (const float*)d_in[10];

    char* w = (char*)d_ws;
    size_t off = 0;
    auto alloc = [&](size_t n) { size_t o = off; off += (n + 15) & ~(size_t)15; return o; };
    float*  kern1  = (float*)(w + alloc((size_t)NCH * KPAD * HIDN * 4));
    float*  kern4  = (float*)(w + alloc((size_t)TM * HIDN * 4));
    double* basisd = (double*)(w + alloc((size_t)BNO * TM * 8));
    int*    ae     = (int*)(w + alloc(EE * 4));
    int*    ai     = (int*)(w + alloc(EI * 4));
    float*  hkpos  = (float*)(w + alloc(64 * 4));
    float*  hkneg  = (float*)(w + alloc(64 * 4));
    float*  spkk   = (float*)(w + alloc(64 * 4));
    double* hkd    = (double*)(w + alloc(64 * 8));
    double* xd     = (double*)(w + alloc((size_t)T_TOT * 8));
    double* thrd   = (double*)(w + alloc((size_t)T_TOT * 8));
    float*  thr32  = (float*)(w + alloc((size_t)T_TOT * 4));
    float*  blo    = (float*)(w + alloc((size_t)(T_TOT + 64) * 4));
    float*  bhi    = (float*)(w + alloc((size_t)(T_TOT + 64) * 4));
    int*    dirty  = (int*)(w + alloc(256 * 4));
    float*  syn    = (float*)(w + alloc((size_t)NCH * SROW * 4));
    float*  out1   = (float*)(w + alloc((size_t)HIDN * T_TOT * 4));
    // total ws use ~53 MB

    k_setup<<<1, 1024, 0, stream>>>(Ce, Ci, Wh, Ws, Ta, ae, ai, hkpos, hkneg, spkk, hkd, basisd);
    k_makekern<<<(NCH * KPAD * HIDN + HIDN * TM + 255) / 256, 256, 0, stream>>>(w1, w4, basisd, kern1, kern4);
    k_route<<<T_TOT / 64, 256, 0, stream>>>(Se, Si, ae, ai, syn);
    k_init<<<(T_TOT + 64 + 255) / 256, 256, 0, stream>>>(blo, bhi, dirty, syn);
    k_conv1<<<(T_TOT + C1T - 1) / C1T, C1THR, 0, stream>>>(syn, kern1, out1);
    k_conv2<<<(T_TOT + TT1 - 1) / TT1, 256, 0, stream>>>(out1, kern4, Th, u, xd, thrd, thr32);
    for (int r = 0; r < 3; ++r)
        k_relax<<<(T_TOT + RTILE - 1) / RTILE, 256, 0, stream>>>(thr32, hkpos, hkneg, blo, bhi);
    k_mark<<<(T_TOT + 1023) / 1024, 1024, 0, stream>>>(blo, bhi, dirty);
    k_cleanup<<<1, 1024, 0, stream>>>(thrd, hkd, dirty, blo, bhi);
    k_out<<<(T_TOT + TT1 - 1) / TT1, 256, 0, stream>>>(blo, spkk, hkd, xd, (float*)d_out);
}

// Round 4
// 1229.144 us; speedup vs baseline: 1.5674x; 1.5674x over previous
//
#include <hip/hip_runtime.h>
#include <math.h>

// ---- problem constants (from reference) ----
#define T_TOT  200000
#define EE     500
#define EI     100
#define SUBN   20
#define NCH    40      // 2*SUB
#define HIDN   20
#define BNO    34
#define TM     101     // basis kernel length
#define TNO    50      // history length / half kernel
#define HBNO   18
#define TT1    256     // t-tile for conv2/output kernels
#define EPSF   2e-5f   // sound margin for interval determinations

// padded syn row: [64 zeros][T][256 zeros]
#define PADL   64
#define PADR   256
#define SROW   (PADL + T_TOT + PADR)   // 200320

// prefiltered G row: G_s[tau] at [s*GROW + tau+50], tau in [-50, T+61]
#define GROW   (T_TOT + 112)           // 200112

// conv1f tiling: 256 threads x 4 t, h split 4 ways (5 h per part)
#define C1T    1024

// relax tiling
#define RTILE  512
#define RHALO  64
#define RRND   3
#define NTILE  ((T_TOT + 1023) / 1024)   // 196

// ======================= setup: assignments, small kernels, basis ============
__global__ void k_setup(const float* __restrict__ Ce, const float* __restrict__ Ci,
                        const float* __restrict__ Wh, const float* __restrict__ Wspk,
                        const float* __restrict__ Tau,
                        int* __restrict__ ae, int* __restrict__ ai,
                        float* __restrict__ hkpos, float* __restrict__ hkneg,
                        float* __restrict__ spkk, float* __restrict__ gtap,
                        double* __restrict__ hkd, double* __restrict__ basisd)
{
    int tid = threadIdx.x;  // block 1024
    if (tid < EE) {
        int a = 0;
        for (int s = 0; s < SUBN; ++s) if (Ce[s * EE + tid] > 0.5f) a = s;
        ae[tid] = a;
    } else if (tid < EE + EI) {
        int e = tid - EE; int a = 0;
        for (int s = 0; s < SUBN; ++s) if (Ci[s * EI + e] > 0.5f) a = s;
        ai[e] = a;
    } else if (tid < 664) {
        // hk_r[j] = hist_kern[TNO - j], j in [1,TNO]; zero-fill rest of 64
        int j = tid - 600;
        double hk = 0.0;
        if (j >= 1 && j <= TNO) {
            int i = TNO - j;
            for (int b = 0; b < HBNO; ++b) {
                double d = (double)i - 3.0 * (double)b;
                hk += (double)Wh[b] * exp(-d * d / 3.0);
            }
        }
        hkd[j] = hk;
        hkpos[j] = (float)fmax(hk, 0.0);
        hkneg[j] = (float)fmin(hk, 0.0);
    } else if (tid < 728) {
        int m = tid - 664; float v = 0.f;
        if (m < TNO) {
            double tau2 = (double)Tau[0] * (double)Tau[0];
            double tt = (double)m / tau2;
            v = (float)(tt * exp(-tt) * (double)Wspk[0] * (double)Wspk[0]);
        }
        spkk[m] = v;
    } else if (tid < 753) {
        int j = tid - 740;                       // j in [-12, 12]
        gtap[tid - 728] = (float)exp(-(double)(j * j) / 3.0);
    }
    // Gaussian basis table (fp64) for kern4 construction
    for (int idx = tid; idx < BNO * TM; idx += blockDim.x) {
        int b = idx / TM, k = idx % TM;
        double d = (double)k - 3.0 * (double)b;
        basisd[idx] = exp(-d * d / 3.0);
    }
}

// ======================= prep: kern4, w1 transpose, edge-tap tables, pads ====
// w1T layout: [(s*34+b)*20 + h]; dtab layout: [(s*24+mi)*20 + h]
//   mi<12 -> syn offset m = mi-62; mi>=12 -> m = mi+39 (i.e. 51..62)
__global__ void k_prep(const float* __restrict__ w1, const float* __restrict__ w4,
                       const double* __restrict__ basisd,
                       float* __restrict__ kern4, float* __restrict__ w1T,
                       float* __restrict__ dtab, float* __restrict__ syn)
{
    int idx = blockIdx.x * 256 + threadIdx.x;
    if (idx < HIDN * TM) {
        int h = idx % HIDN, k = idx / HIDN;
        double acc = 0.0;
        for (int b = 0; b < BNO; ++b) acc += (double)w4[h * BNO + b] * basisd[b * TM + k];
        kern4[k * HIDN + h] = (float)acc;        // [k][h] layout
    } else if (idx < 2020 + NCH * BNO * HIDN) {
        int j = idx - 2020;
        int h = j % HIDN, b = (j / HIDN) % BNO, s = j / (HIDN * BNO);
        w1T[j] = w1[(h * NCH + s) * BNO + b];
    } else if (idx < 29220 + NCH * 24 * HIDN) {
        int j = idx - 29220;
        int h = j % HIDN, mi = (j / HIDN) % 24, s = j / (HIDN * 24);
        int m = (mi < 12) ? (mi - 62) : (mi + 39);
        double acc = 0.0;
        for (int b = 0; b < BNO; ++b) {
            int jj = m + 50 - 3 * b;             // Gaussian tap our G includes
            if (jj >= -12 && jj <= 12)           // (k = jj+3b is outside [0,100] by construction of m)
                acc += (double)w1[(h * NCH + s) * BNO + b] * exp(-(double)(jj * jj) / 3.0);
        }
        dtab[j] = (float)acc;
    } else if (idx < 48420 + NCH * (PADL + PADR)) {
        int j = idx - 48420;
        int r = j / (PADL + PADR), c = j % (PADL + PADR);
        int off = (c < PADL) ? c : (PADL + T_TOT + (c - PADL));
        syn[(size_t)r * SROW + off] = 0.f;
    }
}

// ======================= synapse -> subunit routing ==========================
__global__ __launch_bounds__(256) void k_route(const float* __restrict__ Se,
                                               const float* __restrict__ Si,
                                               const int* __restrict__ ae,
                                               const int* __restrict__ ai,
                                               float* __restrict__ syn)
{
    __shared__ float acc[NCH * 64];
    __shared__ int sae[EE];
    __shared__ int sai[EI];
    int tid = threadIdx.x;
    for (int i = tid; i < NCH * 64; i += 256) acc[i] = 0.f;
    for (int i = tid; i < EE; i += 256) sae[i] = ae[i];
    for (int i = tid; i < EI; i += 256) sai[i] = ai[i];
    __syncthreads();
    int t0 = blockIdx.x * 64;              // T divisible by 64
    int lane = tid & 63, grp = tid >> 6;
    for (int ec = 0; ec < 8; ++ec) {
        int e = ec * 64 + lane;
        if (e < EE) {
            int a = sae[e];
            for (int ts = grp; ts < 64; ts += 4) {
                float v = Se[(size_t)(t0 + ts) * EE + e];   // coalesced across lanes
                if (v != 0.f) atomicAdd(&acc[a * 64 + ts], v);
            }
        }
    }
    for (int ec = 0; ec < 2; ++ec) {
        int e = ec * 64 + lane;
        if (e < EI) {
            int a = sai[e] + SUBN;
            for (int ts = grp; ts < 64; ts += 4) {
                float v = Si[(size_t)(t0 + ts) * EI + e];
                if (v != 0.f) atomicAdd(&acc[a * 64 + ts], v);
            }
        }
    }
    __syncthreads();
    for (int i = tid; i < NCH * 64; i += 256) {
        int s = i >> 6, ts = i & 63;
        syn[(size_t)s * SROW + PADL + t0 + ts] = acc[i];
    }
}

// ======================= Gaussian prefilter: G_s = g (*) syn_s ===============
__global__ __launch_bounds__(256) void k_prefilt(const float* __restrict__ syn,
                                                 const float* __restrict__ gtap,
                                                 float* __restrict__ G)
{
    int gi = blockIdx.x * 256 + threadIdx.x;     // gridDim.y = s
    if (gi >= GROW) return;
    const float* sp = syn + (size_t)blockIdx.y * SROW + PADL + (gi - 50);
    double a = 0.0;
#pragma unroll
    for (int j = -12; j <= 12; ++j)
        a += (double)gtap[j + 12] * (double)sp[j];
    G[(size_t)blockIdx.y * GROW + gi] = (float)a;
}

// ======================= conv1 factorized consumer + leaky_relu ==============
// out1[h,t] = sum_s [ sum_b w1[h,s,b]*G_s[t+3b-50]  -  sum_m d[h,s,m]*syn_s[t+m] ]
// blocks: (tile, part): part owns h in [5*part, 5*part+5), thread owns 4 t.
__global__ __launch_bounds__(256) void k_conv1f(const float* __restrict__ G,
                                                const float* __restrict__ syn,
                                                const float* __restrict__ w1T,
                                                const float* __restrict__ dtab,
                                                float* __restrict__ out1)
{
    int part = blockIdx.x & 3;
    int tile = blockIdx.x >> 2;
    int h0 = part * 5;
    int t = tile * C1T + 4 * threadIdx.x;
    if (t >= T_TOT) return;                      // no LDS/barriers -> safe early exit
    float acc[5][4];
#pragma unroll
    for (int hh = 0; hh < 5; ++hh)
#pragma unroll
        for (int tt = 0; tt < 4; ++tt) acc[hh][tt] = 0.f;

    for (int s = 0; s < NCH; ++s) {
        const float* wp = w1T + (s * BNO) * HIDN + h0;
        const float* Gp = G + (size_t)s * GROW + t;      // index +3b reads G_s[t+3b-50]
        const float* dp = dtab + (s * 24) * HIDN + h0;
        const float* sp = syn + (size_t)s * SROW + PADL + t;
#pragma unroll 2
        for (int b = 0; b < BNO; ++b) {
            float c[5], gv[4];
#pragma unroll
            for (int hh = 0; hh < 5; ++hh) c[hh] = wp[b * HIDN + hh];
#pragma unroll
            for (int tt = 0; tt < 4; ++tt) gv[tt] = Gp[3 * b + tt];
#pragma unroll
            for (int hh = 0; hh < 5; ++hh)
#pragma unroll
                for (int tt = 0; tt < 4; ++tt)
                    acc[hh][tt] = fmaf(c[hh], gv[tt], acc[hh][tt]);
        }
#pragma unroll
        for (int mi = 0; mi < 24; ++mi) {
            int mo = (mi < 12) ? (mi - 62) : (mi + 39);
            float c[5], xv[4];
#pragma unroll
            for (int hh = 0; hh < 5; ++hh) c[hh] = dp[mi * HIDN + hh];
#pragma unroll
            for (int tt = 0; tt < 4; ++tt) xv[tt] = sp[mo + tt];
#pragma unroll
            for (int hh = 0; hh < 5; ++hh)
#pragma unroll
                for (int tt = 0; tt < 4; ++tt)
                    acc[hh][tt] = fmaf(-c[hh], xv[tt], acc[hh][tt]);
        }
    }
#pragma unroll
    for (int hh = 0; hh < 5; ++hh) {
        float4 st;
        float o0 = acc[hh][0], o1 = acc[hh][1], o2 = acc[hh][2], o3 = acc[hh][3];
        st.x = (o0 > 0.f) ? o0 : 0.01f * o0;
        st.y = (o1 > 0.f) ? o1 : 0.01f * o1;
        st.z = (o2 > 0.f) ? o2 : 0.01f * o2;
        st.w = (o3 > 0.f) ? o3 : 0.01f * o3;
        *(float4*)(out1 + (size_t)(h0 + hh) * T_TOT + t) = st;   // t % 4 == 0 -> aligned
    }
}

// ======================= conv2 (fp64 acc) + logit threshold ==================
__global__ __launch_bounds__(256) void k_conv2(const float* __restrict__ out1,
                                               const float* __restrict__ kern4,
                                               const float* __restrict__ Theta,
                                               const float* __restrict__ u,
                                               double* __restrict__ xd,
                                               double* __restrict__ thrd,
                                               float* __restrict__ thr32)
{
    __shared__ float s1[HIDN * (TT1 + 100)];    // 28,480 B
    int tid = threadIdx.x;
    int t0 = blockIdx.x * TT1;
    for (int i = tid; i < HIDN * (TT1 + 100); i += 256) {
        int h = i / (TT1 + 100), x = i % (TT1 + 100);
        int g = t0 + x - TNO;
        s1[i] = (g >= 0 && g < T_TOT) ? out1[(size_t)h * T_TOT + g] : 0.f;
    }
    __syncthreads();
    int t = t0 + tid;
    if (t >= T_TOT) return;
    double acc = 0.0;
    for (int k = 0; k < TM; ++k) {
        const float* kp = kern4 + k * HIDN;
#pragma unroll
        for (int h = 0; h < HIDN; ++h)
            acc = fma((double)s1[h * (TT1 + 100) + tid + k], (double)kp[h], acc);
    }
    double x = acc + (double)Theta[0];
    double uu = (double)u[t];
    // spike  <=>  u < sigmoid(x + a)  <=>  a > logit(u) - x
    double th = (log(uu) - log1p(-uu)) - x;     // u==0 -> -inf -> always spike (correct)
    xd[t] = x; thrd[t] = th; thr32[t] = (float)th;
}

// ======================= interval state init ================================
__global__ void k_init(float* __restrict__ blo, float* __restrict__ bhi,
                       int* __restrict__ dirty)
{
    int i = blockIdx.x * 256 + threadIdx.x;
    if (i < T_TOT + 64) {
        blo[i] = 0.f;                                        // index = t + TNO
        bhi[i] = (i >= TNO && i < T_TOT + TNO) ? 1.f : 0.f;  // unknown = (0,1)
    }
    if (i < 256) dirty[i] = 0;
}

// ======================= sound interval relaxation ==========================
__global__ __launch_bounds__(256) void k_relax(const float* __restrict__ thr32,
                                               const float* __restrict__ hkpos,
                                               const float* __restrict__ hkneg,
                                               float* __restrict__ blo,
                                               float* __restrict__ bhi)
{
    __shared__ float slo[RTILE + RHALO], shi[RTILE + RHALO];
    __shared__ float sth[RTILE + RHALO];
    __shared__ float shp[64], shn[64];
    int tid = threadIdx.x;
    int t0 = blockIdx.x * RTILE;
    for (int i = tid; i < RTILE + RHALO; i += 256) {
        int t = t0 - RHALO + i;
        int g = t + TNO;
        bool ok = (g >= 0 && g < T_TOT + 64);
        slo[i] = ok ? blo[g] : 0.f;
        shi[i] = ok ? bhi[g] : 0.f;
        sth[i] = (t >= 0 && t < T_TOT) ? thr32[t] : 0.f;
    }
    if (tid < 64) { shp[tid] = hkpos[tid]; shn[tid] = hkneg[tid]; }
    __syncthreads();
    for (int r = 0; r < RRND; ++r) {
        for (int i = tid; i < RTILE + RHALO; i += 256) {
            if (i < TNO) continue;                   // needs 50 left neighbors in LDS
            float l = slo[i], h = shi[i];
            if (l == h) continue;
            float lo = 0.f, hi = 0.f;
            for (int j = 1; j <= TNO; ++j) {
                float bl = slo[i - j], bh = shi[i - j];
                float hp = shp[j], hn = shn[j];
                lo = fmaf(hp, bl, lo); lo = fmaf(hn, bh, lo);
                hi = fmaf(hp, bh, hi); hi = fmaf(hn, bl, hi);
            }
            float th = sth[i];
            if (lo > th + EPSF)      slo[i] = 1.f;   // determined spike
            else if (hi < th - EPSF) shi[i] = 0.f;   // determined no-spike
        }
        __syncthreads();
    }
    for (int i = tid; i < RTILE; i += 256) {         // write back interior only
        int t = t0 + i;
        if (t < T_TOT) {
            blo[t + TNO] = slo[RHALO + i];
            bhi[t + TNO] = shi[RHALO + i];
        }
    }
}

// ======================= per-tile unknown counts =============================
__global__ __launch_bounds__(1024) void k_mark(const float* __restrict__ blo,
                                               const float* __restrict__ bhi,
                                               int* __restrict__ dirty)
{
    int t = blockIdx.x * 1024 + threadIdx.x;
    int unk = (t < T_TOT) && (blo[t + TNO] != bhi[t + TNO]);
    int c = __syncthreads_count(unk);
    if (threadIdx.x == 0) dirty[blockIdx.x] = c;
}

// ======================= compact unknowns to sorted list =====================
__global__ __launch_bounds__(1024) void k_compact(const float* __restrict__ blo,
                                                  const float* __restrict__ bhi,
                                                  const int* __restrict__ dirty,
                                                  int* __restrict__ list,
                                                  int* __restrict__ utot)
{
    __shared__ int wsum[16];
    __shared__ int sbase;
    int tid = threadIdx.x;
    int t = blockIdx.x * 1024 + tid;
    int unk = (t < T_TOT) && (blo[t + TNO] != bhi[t + TNO]);
    unsigned long long m = __ballot(unk);
    int lane = tid & 63, wv = tid >> 6;
    int lr = __popcll(m & ((1ull << lane) - 1ull));
    if (lane == 0) wsum[wv] = __popcll(m);
    if (tid == 0) {
        int b = 0;
        for (int k = 0; k < (int)blockIdx.x; ++k) b += dirty[k];
        sbase = b;
        if (blockIdx.x == 0) {
            int tot = 0;
            for (int k = 0; k < NTILE; ++k) tot += dirty[k];
            utot[0] = tot;
        }
    }
    __syncthreads();
    if (tid == 0) {
        int r = 0;
        for (int k = 0; k < 16; ++k) { int c = wsum[k]; wsum[k] = r; r += c; }
    }
    __syncthreads();
    if (unk) list[sbase + wsum[wv] + lr] = t;
}

// ======================= parallel known-history dots (fp64) ==================
__global__ __launch_bounds__(256) void k_afix(const int* __restrict__ list,
                                              const int* __restrict__ utot,
                                              const float* __restrict__ blo,
                                              const double* __restrict__ hkd,
                                              double* __restrict__ afix)
{
    int i = blockIdx.x * 256 + threadIdx.x;
    if (i >= utot[0]) return;
    int t = list[i];
    double a = 0.0;
    for (int j = 1; j <= TNO; ++j)
        a += hkd[j] * (double)blo[t - j + TNO];   // unknowns read as 0
    afix[i] = a;
}

// ======================= sequential resolve (single wave, LDS-batched) =======
__global__ __launch_bounds__(64) void k_resolve(const int* __restrict__ list,
                                                const double* __restrict__ afix,
                                                const double* __restrict__ thrd,
                                                const double* __restrict__ hkd,
                                                const int* __restrict__ utot,
                                                float* __restrict__ blo,
                                                float* __restrict__ bhi)
{
    __shared__ int    lt[128];
    __shared__ double la[128];
    __shared__ double lth[128];
    __shared__ int    lb[128];
    __shared__ double shk[64];
    int lane = threadIdx.x;
    shk[lane] = (lane >= 1 && lane <= TNO) ? hkd[lane] : 0.0;
    int U = utot[0];
    for (int i0 = 0; i0 < U; i0 += 64) {
        int i = i0 + lane;
        if (i < U) {
            int t = list[i];
            lt[i & 127] = t;
            la[i & 127] = afix[i];
            lth[i & 127] = thrd[t];
        }
        __syncthreads();
        if (lane == 0) {
            int n = (U - i0 < 64) ? (U - i0) : 64;
            for (int q = 0; q < n; ++q) {
                int ii = i0 + q, c = ii & 127;
                int t = lt[c];
                double a = la[c];
                for (int k = ii - 1; k >= 0; --k) {       // unknown predecessors in window
                    int ck = k & 127;
                    int tk = lt[ck];
                    if (tk < t - TNO) break;
                    if (lb[ck]) a += shk[t - tk];
                }
                int sbit = (a > lth[c]) ? 1 : 0;
                lb[c] = sbit;
                float f = (float)sbit;
                blo[t + TNO] = f; bhi[t + TNO] = f;
            }
        }
        __syncthreads();
    }
}

// ======================= outputs: spk_filt + prob_out ========================
__global__ __launch_bounds__(256) void k_out(const float* __restrict__ blo,
                                             const float* __restrict__ spkk,
                                             const double* __restrict__ hkd,
                                             const double* __restrict__ xd,
                                             float* __restrict__ outp)
{
    __shared__ float sb[TT1 + 64];
    __shared__ float ssp[64];
    __shared__ double shk[64];
    int tid = threadIdx.x;
    int t0 = blockIdx.x * TT1;
    for (int i = tid; i < TT1 + TNO; i += 256) {
        int g = t0 + i;
        sb[i] = (g < T_TOT + 64) ? blo[g] : 0.f;
    }
    if (tid < 64) { ssp[tid] = spkk[tid]; shk[tid] = hkd[tid]; }
    __syncthreads();
    int t = t0 + tid;
    if (t >= T_TOT) return;
    float filt = 0.f;
    double a = 0.0;
    for (int m = 1; m <= TNO; ++m) {
        float b = sb[tid + TNO - m];             // spk[t-m]
        filt = fmaf(b, ssp[m - 1], filt);        // spk_kern[m-1]
        a += shk[m] * (double)b;                 // hist feedback (exact)
    }
    double p = 1.0 / (1.0 + exp(-(xd[t] + a)));
    outp[t] = filt;
    outp[T_TOT + t] = (float)p;
}

// ======================= launcher ===========================================
extern "C" void kernel_launch(void* const* d_in, const int* in_sizes, int n_in,
                              void* d_out, int out_size, void* d_ws, size_t ws_size,
                              hipStream_t stream)
{
    (void)in_sizes; (void)n_in; (void)out_size; (void)ws_size;
    const float* Se = (const float*)d_in[0];
    const float* Si = (const float*)d_in[1];
    const float* Ce = (const float*)d_in[2];
    const float* Ci = (const float*)d_in[3];
    const float* w1 = (const float*)d_in[4];
    const float* w4 = (const float*)d_in[5];
    const float* Wh = (const float*)d_in[6];
    const float* Th = (const float*)d_in[7];
    const float* Ws = (const float*)d_in[8];
    const float* Ta = (const float*)d_in[9];
    const float* u  = (const float*)d_in[10];

    char* w = (char*)d_ws;
    size_t off = 0;
    auto alloc = [&](size_t n) { size_t o = off; off += (n + 15) & ~(size_t)15; return o; };

    // G zone first: 32 MB, reused after conv1f for the scan/decision state
    size_t gzone = alloc((size_t)NCH * GROW * 4);
    float*  G     = (float*)(w + gzone);
    {   // overlay (all used only after conv1f is done with G)
        char* z = w + gzone; size_t zo = 0;
        auto za = [&](size_t n) { size_t o = zo; zo += (n + 15) & ~(size_t)15; return o; };
        (void)za;
    }
    double* xd    = (double*)(w + gzone);                                   // 1.6 MB
    double* thrd  = (double*)(w + gzone + 1600000);                         // 1.6 MB
    float*  thr32 = (float*)(w + gzone + 3200000);                          // 0.8 MB
    float*  blo   = (float*)(w + gzone + 4000000);                          // 0.8+ MB
    float*  bhi   = (float*)(w + gzone + 4801024);
    int*    dirty = (int*)(w + gzone + 5602048);                            // 1 KB+
    int*    list  = (int*)(w + gzone + 5604096);                            // 0.8 MB
    double* afix  = (double*)(w + gzone + 6404096);                         // 1.6 MB
    int*    utot  = dirty + 200;

    float*  syn    = (float*)(w + alloc((size_t)NCH * SROW * 4));           // 32 MB
    float*  out1   = (float*)(w + alloc((size_t)HIDN * T_TOT * 4));         // 16 MB
    float*  kern4  = (float*)(w + alloc((size_t)TM * HIDN * 4));
    float*  w1T    = (float*)(w + alloc((size_t)NCH * BNO * HIDN * 4));
    float*  dtab   = (float*)(w + alloc((size_t)NCH * 24 * HIDN * 4));
    double* basisd = (double*)(w + alloc((size_t)BNO * TM * 8));
    int*    ae     = (int*)(w + alloc(EE * 4));
    int*    ai     = (int*)(w + alloc(EI * 4));
    float*  hkpos  = (float*)(w + alloc(64 * 4));
    float*  hkneg  = (float*)(w + alloc(64 * 4));
    float*  spkk   = (float*)(w + alloc(64 * 4));
    float*  gtap   = (float*)(w + alloc(32 * 4));
    double* hkd    = (double*)(w + alloc(64 * 8));
    // total ws use ~81 MB

    k_setup<<<1, 1024, 0, stream>>>(Ce, Ci, Wh, Ws, Ta, ae, ai, hkpos, hkneg, spkk, gtap, hkd, basisd);
    k_prep<<<(48420 + NCH * (PADL + PADR) + 255) / 256, 256, 0, stream>>>(w1, w4, basisd, kern4, w1T, dtab, syn);
    k_route<<<T_TOT / 64, 256, 0, stream>>>(Se, Si, ae, ai, syn);
    dim3 pg((GROW + 255) / 256, NCH);
    k_prefilt<<<pg, 256, 0, stream>>>(syn, gtap, G);
    k_conv1f<<<((T_TOT + C1T - 1) / C1T) * 4, 256, 0, stream>>>(G, syn, w1T, dtab, out1);
    // ---- G dead from here; its zone now holds xd/thrd/thr32/blo/bhi/dirty/list/afix ----
    k_conv2<<<(T_TOT + TT1 - 1) / TT1, 256, 0, stream>>>(out1, kern4, Th, u, xd, thrd, thr32);
    k_init<<<(T_TOT + 64 + 255) / 256, 256, 0, stream>>>(blo, bhi, dirty);
    for (int r = 0; r < 4; ++r)
        k_relax<<<(T_TOT + RTILE - 1) / RTILE, 256, 0, stream>>>(thr32, hkpos, hkneg, blo, bhi);
    k_mark<<<NTILE, 1024, 0, stream>>>(blo, bhi, dirty);
    k_compact<<<NTILE, 1024, 0, stream>>>(blo, bhi, dirty, list, utot);
    k_afix<<<(T_TOT + 255) / 256, 256, 0, stream>>>(list, utot, blo, hkd, afix);
    k_resolve<<<1, 64, 0, stream>>>(list, afix, thrd, hkd, utot, blo, bhi);
    k_out<<<(T_TOT + TT1 - 1) / TT1, 256, 0, stream>>>(blo, spkk, hkd, xd, (float*)d_out);
}

// Round 5
// 1186.967 us; speedup vs baseline: 1.6231x; 1.0355x over previous
//
#include <hip/hip_runtime.h>
#include <math.h>

// ---- problem constants (from reference) ----
#define T_TOT  200000
#define EE     500
#define EI     100
#define SUBN   20
#define NCH    40      // 2*SUB
#define HIDN   20
#define BNO    34
#define TM     101     // basis kernel length
#define TNO    50      // history length / half kernel
#define HBNO   18
#define TT1    256     // t-tile for conv2/output kernels
#define EPSF   2e-5f   // sound margin for interval determinations

// padded syn row: [64 zeros][T][256 zeros]
#define PADL   64
#define PADR   256
#define SROW   (PADL + T_TOT + PADR)   // 200320

// prefiltered G row: G_s[tau] at [s*GROW + tau+50], tau in [-50, T+61]
#define GROW   (T_TOT + 112)           // 200112

// relax tiling
#define RTILE  512
#define RHALO  64
#define RRND   3
#define NTILE  ((T_TOT + 1023) / 1024)   // 196

// ======================= setup: assignments, small kernels, basis ============
__global__ void k_setup(const float* __restrict__ Ce, const float* __restrict__ Ci,
                        const float* __restrict__ Wh, const float* __restrict__ Wspk,
                        const float* __restrict__ Tau,
                        int* __restrict__ ae, int* __restrict__ ai,
                        float* __restrict__ hkpos, float* __restrict__ hkneg,
                        float* __restrict__ spkk, float* __restrict__ gtap,
                        double* __restrict__ hkd, double* __restrict__ basisd)
{
    int tid = threadIdx.x;  // block 1024
    if (tid < EE) {
        int a = 0;
        for (int s = 0; s < SUBN; ++s) if (Ce[s * EE + tid] > 0.5f) a = s;
        ae[tid] = a;
    } else if (tid < EE + EI) {
        int e = tid - EE; int a = 0;
        for (int s = 0; s < SUBN; ++s) if (Ci[s * EI + e] > 0.5f) a = s;
        ai[e] = a;
    } else if (tid < 664) {
        // hk_r[j] = hist_kern[TNO - j], j in [1,TNO]; zero-fill rest of 64
        int j = tid - 600;
        double hk = 0.0;
        if (j >= 1 && j <= TNO) {
            int i = TNO - j;
            for (int b = 0; b < HBNO; ++b) {
                double d = (double)i - 3.0 * (double)b;
                hk += (double)Wh[b] * exp(-d * d / 3.0);
            }
        }
        hkd[j] = hk;
        hkpos[j] = (float)fmax(hk, 0.0);
        hkneg[j] = (float)fmin(hk, 0.0);
    } else if (tid < 728) {
        int m = tid - 664; float v = 0.f;
        if (m < TNO) {
            double tau2 = (double)Tau[0] * (double)Tau[0];
            double tt = (double)m / tau2;
            v = (float)(tt * exp(-tt) * (double)Wspk[0] * (double)Wspk[0]);
        }
        spkk[m] = v;
    } else if (tid < 753) {
        int j = tid - 740;                       // j in [-12, 12]
        gtap[tid - 728] = (float)exp(-(double)(j * j) / 3.0);
    }
    // Gaussian basis table (fp64) for kern4 construction
    for (int idx = tid; idx < BNO * TM; idx += blockDim.x) {
        int b = idx / TM, k = idx % TM;
        double d = (double)k - 3.0 * (double)b;
        basisd[idx] = exp(-d * d / 3.0);
    }
}

// ======================= prep: kern4, w1 transpose, edge-tap tables, pads ====
// w1T layout: [(s*34+b)*20 + h]; dtab layout: [(s*24+mi)*20 + h]
//   mi<12 -> syn offset m = mi-62; mi>=12 -> m = mi+39 (i.e. 51..62)
__global__ void k_prep(const float* __restrict__ w1, const float* __restrict__ w4,
                       const double* __restrict__ basisd,
                       float* __restrict__ kern4, float* __restrict__ w1T,
                       float* __restrict__ dtab, float* __restrict__ syn)
{
    int idx = blockIdx.x * 256 + threadIdx.x;
    if (idx < HIDN * TM) {
        int h = idx % HIDN, k = idx / HIDN;
        double acc = 0.0;
        for (int b = 0; b < BNO; ++b) acc += (double)w4[h * BNO + b] * basisd[b * TM + k];
        kern4[k * HIDN + h] = (float)acc;        // [k][h] layout
    } else if (idx < 2020 + NCH * BNO * HIDN) {
        int j = idx - 2020;
        int h = j % HIDN, b = (j / HIDN) % BNO, s = j / (HIDN * BNO);
        w1T[j] = w1[(h * NCH + s) * BNO + b];
    } else if (idx < 29220 + NCH * 24 * HIDN) {
        int j = idx - 29220;
        int h = j % HIDN, mi = (j / HIDN) % 24, s = j / (HIDN * 24);
        int m = (mi < 12) ? (mi - 62) : (mi + 39);
        double acc = 0.0;
        for (int b = 0; b < BNO; ++b) {
            int jj = m + 50 - 3 * b;             // Gaussian tap our G includes
            if (jj >= -12 && jj <= 12)           // (k = jj+3b is outside [0,100] by construction of m)
                acc += (double)w1[(h * NCH + s) * BNO + b] * exp(-(double)(jj * jj) / 3.0);
        }
        dtab[j] = (float)acc;
    } else if (idx < 48420 + NCH * (PADL + PADR)) {
        int j = idx - 48420;
        int r = j / (PADL + PADR), c = j % (PADL + PADR);
        int off = (c < PADL) ? c : (PADL + T_TOT + (c - PADL));
        syn[(size_t)r * SROW + off] = 0.f;
    }
}

// ======================= synapse -> subunit routing (float4 loads) ===========
__global__ __launch_bounds__(256) void k_route(const float* __restrict__ Se,
                                               const float* __restrict__ Si,
                                               const int* __restrict__ ae,
                                               const int* __restrict__ ai,
                                               float* __restrict__ syn)
{
    __shared__ float acc[NCH * 64];
    __shared__ int sae[EE];
    __shared__ int sai[EI];
    int tid = threadIdx.x;
    for (int i = tid; i < NCH * 64; i += 256) acc[i] = 0.f;
    for (int i = tid; i < EE; i += 256) sae[i] = ae[i];
    for (int i = tid; i < EI; i += 256) sai[i] = ai[i];
    __syncthreads();
    int t0 = blockIdx.x * 64;              // T divisible by 64
    int lane = tid & 63, grp = tid >> 6;
    for (int ec = 0; ec < 2; ++ec) {
        int ev = ec * 64 + lane;           // float4 index; 125 cover 500 floats
        if (ev < EE / 4) {
            int e = 4 * ev;
            int a0 = sae[e], a1 = sae[e + 1], a2 = sae[e + 2], a3 = sae[e + 3];
            for (int ts = grp; ts < 64; ts += 4) {
                float4 v = *(const float4*)(Se + (size_t)(t0 + ts) * EE + e);  // 2000,16 | 16 -> aligned
                if (v.x != 0.f) atomicAdd(&acc[a0 * 64 + ts], v.x);
                if (v.y != 0.f) atomicAdd(&acc[a1 * 64 + ts], v.y);
                if (v.z != 0.f) atomicAdd(&acc[a2 * 64 + ts], v.z);
                if (v.w != 0.f) atomicAdd(&acc[a3 * 64 + ts], v.w);
            }
        }
    }
    {
        int ev = lane;                     // 25 cover 100 floats
        if (ev < EI / 4) {
            int e = 4 * ev;
            int a0 = sai[e] + SUBN, a1 = sai[e + 1] + SUBN, a2 = sai[e + 2] + SUBN, a3 = sai[e + 3] + SUBN;
            for (int ts = grp; ts < 64; ts += 4) {
                float4 v = *(const float4*)(Si + (size_t)(t0 + ts) * EI + e);
                if (v.x != 0.f) atomicAdd(&acc[a0 * 64 + ts], v.x);
                if (v.y != 0.f) atomicAdd(&acc[a1 * 64 + ts], v.y);
                if (v.z != 0.f) atomicAdd(&acc[a2 * 64 + ts], v.z);
                if (v.w != 0.f) atomicAdd(&acc[a3 * 64 + ts], v.w);
            }
        }
    }
    __syncthreads();
    for (int i = tid; i < NCH * 64; i += 256) {
        int s = i >> 6, ts = i & 63;
        syn[(size_t)s * SROW + PADL + t0 + ts] = acc[i];
    }
}

// ======================= Gaussian prefilter: G_s = g (*) syn_s ===============
__global__ __launch_bounds__(256) void k_prefilt(const float* __restrict__ syn,
                                                 const float* __restrict__ gtap,
                                                 float* __restrict__ G)
{
    int gi = blockIdx.x * 256 + threadIdx.x;     // gridDim.y = s
    if (gi >= GROW) return;
    const float* sp = syn + (size_t)blockIdx.y * SROW + PADL + (gi - 50);
    double a = 0.0;
#pragma unroll
    for (int j = -12; j <= 12; ++j)
        a += (double)gtap[j + 12] * (double)sp[j];
    G[(size_t)blockIdx.y * GROW + gi] = (float)a;
}

// ======================= conv1 factorized consumer + leaky_relu ==============
// out1[h,t] = sum_s [ sum_b w1[h,s,b]*G_s[t+3b-50]  -  sum_m d[h,s,m]*syn_s[t+m] ]
// 1 t per thread, all 20 h -> 20 FMA per G-load; coefficients via s_load.
__global__ __launch_bounds__(256, 3) void k_conv1f(const float* __restrict__ G,
                                                   const float* __restrict__ syn,
                                                   const float* __restrict__ w1T,
                                                   const float* __restrict__ dtab,
                                                   float* __restrict__ out1)
{
    int t = blockIdx.x * 256 + threadIdx.x;
    if (t >= T_TOT) return;
    float acc[HIDN];
#pragma unroll
    for (int h = 0; h < HIDN; ++h) acc[h] = 0.f;

    for (int s = 0; s < NCH; ++s) {
        const float* wp = w1T + (s * BNO) * HIDN;        // block-uniform -> s_load
        const float* Gp = G + (size_t)s * GROW + t;      // Gp[3b] = G_s[t+3b-50]
        const float* dp = dtab + (s * 24) * HIDN;
        const float* sp = syn + (size_t)s * SROW + PADL + t;
#pragma unroll 2
        for (int b = 0; b < BNO; ++b) {
            float gv = Gp[3 * b];
#pragma unroll
            for (int h = 0; h < HIDN; ++h)
                acc[h] = fmaf(wp[b * HIDN + h], gv, acc[h]);
        }
#pragma unroll 2
        for (int mi = 0; mi < 12; ++mi) {
            float xv = sp[mi - 62];
#pragma unroll
            for (int h = 0; h < HIDN; ++h)
                acc[h] = fmaf(-dp[mi * HIDN + h], xv, acc[h]);
        }
#pragma unroll 2
        for (int mi = 12; mi < 24; ++mi) {
            float xv = sp[mi + 39];
#pragma unroll
            for (int h = 0; h < HIDN; ++h)
                acc[h] = fmaf(-dp[mi * HIDN + h], xv, acc[h]);
        }
    }
#pragma unroll
    for (int h = 0; h < HIDN; ++h) {
        float o = acc[h];
        out1[(size_t)h * T_TOT + t] = (o > 0.f) ? o : 0.01f * o;
    }
}

// ======================= conv2 (fp64 acc) + logit threshold ==================
__global__ __launch_bounds__(256) void k_conv2(const float* __restrict__ out1,
                                               const float* __restrict__ kern4,
                                               const float* __restrict__ Theta,
                                               const float* __restrict__ u,
                                               double* __restrict__ xd,
                                               double* __restrict__ thrd,
                                               float* __restrict__ thr32)
{
    __shared__ float s1[HIDN * (TT1 + 100)];    // 28,480 B
    int tid = threadIdx.x;
    int t0 = blockIdx.x * TT1;
    for (int i = tid; i < HIDN * (TT1 + 100); i += 256) {
        int h = i / (TT1 + 100), x = i % (TT1 + 100);
        int g = t0 + x - TNO;
        s1[i] = (g >= 0 && g < T_TOT) ? out1[(size_t)h * T_TOT + g] : 0.f;
    }
    __syncthreads();
    int t = t0 + tid;
    if (t >= T_TOT) return;
    double acc = 0.0;
    for (int k = 0; k < TM; ++k) {
        const float* kp = kern4 + k * HIDN;
#pragma unroll
        for (int h = 0; h < HIDN; ++h)
            acc = fma((double)s1[h * (TT1 + 100) + tid + k], (double)kp[h], acc);
    }
    double x = acc + (double)Theta[0];
    double uu = (double)u[t];
    // spike  <=>  u < sigmoid(x + a)  <=>  a > logit(u) - x
    double th = (log(uu) - log1p(-uu)) - x;     // u==0 -> -inf -> always spike (correct)
    xd[t] = x; thrd[t] = th; thr32[t] = (float)th;
}

// ======================= interval state init ================================
__global__ void k_init(float* __restrict__ blo, float* __restrict__ bhi,
                       int* __restrict__ dirty)
{
    int i = blockIdx.x * 256 + threadIdx.x;
    if (i < T_TOT + 64) {
        blo[i] = 0.f;                                        // index = t + TNO
        bhi[i] = (i >= TNO && i < T_TOT + TNO) ? 1.f : 0.f;  // unknown = (0,1)
    }
    if (i < 256) dirty[i] = 0;
}

// ======================= sound interval relaxation ==========================
__global__ __launch_bounds__(256) void k_relax(const float* __restrict__ thr32,
                                               const float* __restrict__ hkpos,
                                               const float* __restrict__ hkneg,
                                               float* __restrict__ blo,
                                               float* __restrict__ bhi)
{
    __shared__ float slo[RTILE + RHALO], shi[RTILE + RHALO];
    __shared__ float sth[RTILE + RHALO];
    __shared__ float shp[64], shn[64];
    int tid = threadIdx.x;
    int t0 = blockIdx.x * RTILE;
    for (int i = tid; i < RTILE + RHALO; i += 256) {
        int t = t0 - RHALO + i;
        int g = t + TNO;
        bool ok = (g >= 0 && g < T_TOT + 64);
        slo[i] = ok ? blo[g] : 0.f;
        shi[i] = ok ? bhi[g] : 0.f;
        sth[i] = (t >= 0 && t < T_TOT) ? thr32[t] : 0.f;
    }
    if (tid < 64) { shp[tid] = hkpos[tid]; shn[tid] = hkneg[tid]; }
    __syncthreads();
    for (int r = 0; r < RRND; ++r) {
        for (int i = tid; i < RTILE + RHALO; i += 256) {
            if (i < TNO) continue;                   // needs 50 left neighbors in LDS
            float l = slo[i], h = shi[i];
            if (l == h) continue;
            float lo = 0.f, hi = 0.f;
            for (int j = 1; j <= TNO; ++j) {
                float bl = slo[i - j], bh = shi[i - j];
                float hp = shp[j], hn = shn[j];
                lo = fmaf(hp, bl, lo); lo = fmaf(hn, bh, lo);
                hi = fmaf(hp, bh, hi); hi = fmaf(hn, bl, hi);
            }
            float th = sth[i];
            if (lo > th + EPSF)      slo[i] = 1.f;   // determined spike
            else if (hi < th - EPSF) shi[i] = 0.f;   // determined no-spike
        }
        __syncthreads();
    }
    for (int i = tid; i < RTILE; i += 256) {         // write back interior only
        int t = t0 + i;
        if (t < T_TOT) {
            blo[t + TNO] = slo[RHALO + i];
            bhi[t + TNO] = shi[RHALO + i];
        }
    }
}

// ======================= per-tile unknown counts =============================
__global__ __launch_bounds__(1024) void k_mark(const float* __restrict__ blo,
                                               const float* __restrict__ bhi,
                                               int* __restrict__ dirty)
{
    int t = blockIdx.x * 1024 + threadIdx.x;
    int unk = (t < T_TOT) && (blo[t + TNO] != bhi[t + TNO]);
    int c = __syncthreads_count(unk);
    if (threadIdx.x == 0) dirty[blockIdx.x] = c;
}

// ======================= compact unknowns to sorted list =====================
__global__ __launch_bounds__(1024) void k_compact(const float* __restrict__ blo,
                                                  const float* __restrict__ bhi,
                                                  const int* __restrict__ dirty,
                                                  int* __restrict__ list,
                                                  int* __restrict__ utot)
{
    __shared__ int wsum[16];
    __shared__ int sd[NTILE];
    __shared__ int sbase;
    int tid = threadIdx.x;
    if (tid < NTILE) sd[tid] = dirty[tid];
    int t = blockIdx.x * 1024 + tid;
    int unk = (t < T_TOT) && (blo[t + TNO] != bhi[t + TNO]);
    unsigned long long m = __ballot(unk);
    int lane = tid & 63, wv = tid >> 6;
    int lr = __popcll(m & ((1ull << lane) - 1ull));
    if (lane == 0) wsum[wv] = __popcll(m);
    __syncthreads();
    if (tid == 0) {
        int b = 0;
        for (int k = 0; k < (int)blockIdx.x; ++k) b += sd[k];
        sbase = b;
        if (blockIdx.x == 0) {
            int tot = 0;
            for (int k = 0; k < NTILE; ++k) tot += sd[k];
            utot[0] = tot;
        }
        int r = 0;
        for (int k = 0; k < 16; ++k) { int c = wsum[k]; wsum[k] = r; r += c; }
    }
    __syncthreads();
    if (unk) list[sbase + wsum[wv] + lr] = t;
}

// ======================= parallel known-history dots (fp64) ==================
__global__ __launch_bounds__(256) void k_afix(const int* __restrict__ list,
                                              const int* __restrict__ utot,
                                              const float* __restrict__ blo,
                                              const double* __restrict__ hkd,
                                              double* __restrict__ afix)
{
    int i = blockIdx.x * 256 + threadIdx.x;
    if (i >= utot[0]) return;
    int t = list[i];
    double a = 0.0;
    for (int j = 1; j <= TNO; ++j)
        a += hkd[j] * (double)blo[t - j + TNO];   // unknowns read as 0
    afix[i] = a;
}

// ======================= chain heads (gap > TNO splits) ======================
__global__ __launch_bounds__(256) void k_chain(const int* __restrict__ list,
                                               int* __restrict__ utot,
                                               int* __restrict__ chead)
{
    __shared__ int wcnt[4];
    __shared__ int base_s;
    int tid = threadIdx.x, lane = tid & 63, wv = tid >> 6;
    int U = utot[0];
    if (tid == 0) base_s = 0;
    __syncthreads();
    for (int b0 = 0; b0 < U; b0 += 256) {
        int i = b0 + tid;
        int head = 0;
        if (i < U) head = (i == 0) || (list[i] - list[i - 1] > TNO);
        unsigned long long m = __ballot(head);
        int pre = __popcll(m & ((1ull << lane) - 1ull));
        if (lane == 0) wcnt[wv] = __popcll(m);
        __syncthreads();
        int wbase = 0;
        for (int k = 0; k < wv; ++k) wbase += wcnt[k];
        int tot = wcnt[0] + wcnt[1] + wcnt[2] + wcnt[3];
        if (head) chead[base_s + wbase + pre] = i;
        __syncthreads();
        if (tid == 0) base_s += tot;
        __syncthreads();
    }
    if (tid == 0) utot[1] = base_s;
}

// ======================= parallel exact resolve (one thread per chain) =======
// Chains are >TNO apart -> independent. Within a chain, the walk-back over
// list predecessors with dt<=TNO is exactly the sequential recurrence (fp64).
__global__ __launch_bounds__(256) void k_cresolve(const int* __restrict__ list,
                                                  const int* __restrict__ chead,
                                                  const double* __restrict__ afix,
                                                  const double* __restrict__ thrd,
                                                  const double* __restrict__ hkd,
                                                  const int* __restrict__ utot,
                                                  int* bits,
                                                  float* __restrict__ blo,
                                                  float* __restrict__ bhi)
{
    __shared__ double shk[64];
    if (threadIdx.x < 64)
        shk[threadIdx.x] = (threadIdx.x >= 1 && threadIdx.x <= TNO) ? hkd[threadIdx.x] : 0.0;
    __syncthreads();
    int c = blockIdx.x * 256 + threadIdx.x;
    int nch = utot[1];
    if (c >= nch) return;
    int i0 = chead[c];
    int i1 = (c + 1 < nch) ? chead[c + 1] : utot[0];
    for (int i = i0; i < i1; ++i) {
        int t = list[i];
        double a = afix[i];
        for (int k = i - 1; k >= i0; --k) {     // unknown predecessors (same chain)
            int dt = t - list[k];
            if (dt > TNO) break;
            if (bits[k]) a += shk[dt];
        }
        int sb = (a > thrd[t]) ? 1 : 0;
        bits[i] = sb;
        float f = (float)sb;
        blo[t + TNO] = f;
        bhi[t + TNO] = f;
    }
}

// ======================= outputs: spk_filt + prob_out ========================
__global__ __launch_bounds__(256) void k_out(const float* __restrict__ blo,
                                             const float* __restrict__ spkk,
                                             const double* __restrict__ hkd,
                                             const double* __restrict__ xd,
                                             float* __restrict__ outp)
{
    __shared__ float sb[TT1 + 64];
    __shared__ float ssp[64];
    __shared__ double shk[64];
    int tid = threadIdx.x;
    int t0 = blockIdx.x * TT1;
    for (int i = tid; i < TT1 + TNO; i += 256) {
        int g = t0 + i;
        sb[i] = (g < T_TOT + 64) ? blo[g] : 0.f;
    }
    if (tid < 64) { ssp[tid] = spkk[tid]; shk[tid] = hkd[tid]; }
    __syncthreads();
    int t = t0 + tid;
    if (t >= T_TOT) return;
    float filt = 0.f;
    double a = 0.0;
    for (int m = 1; m <= TNO; ++m) {
        float b = sb[tid + TNO - m];             // spk[t-m]
        filt = fmaf(b, ssp[m - 1], filt);        // spk_kern[m-1]
        a += shk[m] * (double)b;                 // hist feedback (exact)
    }
    double p = 1.0 / (1.0 + exp(-(xd[t] + a)));
    outp[t] = filt;
    outp[T_TOT + t] = (float)p;
}

// ======================= launcher ===========================================
extern "C" void kernel_launch(void* const* d_in, const int* in_sizes, int n_in,
                              void* d_out, int out_size, void* d_ws, size_t ws_size,
                              hipStream_t stream)
{
    (void)in_sizes; (void)n_in; (void)out_size; (void)ws_size;
    const float* Se = (const float*)d_in[0];
    const float* Si = (const float*)d_in[1];
    const float* Ce = (const float*)d_in[2];
    const float* Ci = (const float*)d_in[3];
    const float* w1 = (const float*)d_in[4];
    const float* w4 = (const float*)d_in[5];
    const float* Wh = (const float*)d_in[6];
    const float* Th = (const float*)d_in[7];
    const float* Ws = (const float*)d_in[8];
    const float* Ta = (const float*)d_in[9];
    const float* u  = (const float*)d_in[10];

    char* w = (char*)d_ws;
    size_t off = 0;
    auto alloc = [&](size_t n) { size_t o = off; off += (n + 15) & ~(size_t)15; return o; };

    // G zone first: 32 MB, overlaid after conv1f with the scan/decision state
    size_t gzone = alloc((size_t)NCH * GROW * 4);          // 32,017,920 B
    float*  G     = (float*)(w + gzone);
    double* xd    = (double*)(w + gzone);                  // 1,600,000
    double* thrd  = (double*)(w + gzone + 1600000);        // 1,600,000
    float*  thr32 = (float*)(w + gzone + 3200000);         //   800,000
    float*  blo   = (float*)(w + gzone + 4000000);         //   800,256
    float*  bhi   = (float*)(w + gzone + 4800512);         //   800,256
    int*    dirty = (int*)(w + gzone + 5600768);           //     1,024
    int*    list  = (int*)(w + gzone + 5601792);           //   800,000
    double* afix  = (double*)(w + gzone + 6401792);        // 1,600,000 (8-aligned)
    int*    chead = (int*)(w + gzone + 8001792);           //   800,008
    int*    bits  = (int*)(w + gzone + 8801800);           //   800,000
    int*    utot  = dirty + 200;                           // utot[0]=U, utot[1]=nchains

    float*  syn    = (float*)(w + alloc((size_t)NCH * SROW * 4));   // 32 MB
    float*  out1   = (float*)(w + alloc((size_t)HIDN * T_TOT * 4)); // 16 MB
    float*  kern4  = (float*)(w + alloc((size_t)TM * HIDN * 4));
    float*  w1T    = (float*)(w + alloc((size_t)NCH * BNO * HIDN * 4));
    float*  dtab   = (float*)(w + alloc((size_t)NCH * 24 * HIDN * 4));
    double* basisd = (double*)(w + alloc((size_t)BNO * TM * 8));
    int*    ae     = (int*)(w + alloc(EE * 4));
    int*    ai     = (int*)(w + alloc(EI * 4));
    float*  hkpos  = (float*)(w + alloc(64 * 4));
    float*  hkneg  = (float*)(w + alloc(64 * 4));
    float*  spkk   = (float*)(w + alloc(64 * 4));
    float*  gtap   = (float*)(w + alloc(32 * 4));
    double* hkd    = (double*)(w + alloc(64 * 8));
    // total ws use ~81 MB

    k_setup<<<1, 1024, 0, stream>>>(Ce, Ci, Wh, Ws, Ta, ae, ai, hkpos, hkneg, spkk, gtap, hkd, basisd);
    k_prep<<<(48420 + NCH * (PADL + PADR) + 255) / 256, 256, 0, stream>>>(w1, w4, basisd, kern4, w1T, dtab, syn);
    k_route<<<T_TOT / 64, 256, 0, stream>>>(Se, Si, ae, ai, syn);
    dim3 pg((GROW + 255) / 256, NCH);
    k_prefilt<<<pg, 256, 0, stream>>>(syn, gtap, G);
    k_conv1f<<<(T_TOT + 255) / 256, 256, 0, stream>>>(G, syn, w1T, dtab, out1);
    // ---- G dead from here; its zone now holds the decision state ----
    k_conv2<<<(T_TOT + TT1 - 1) / TT1, 256, 0, stream>>>(out1, kern4, Th, u, xd, thrd, thr32);
    k_init<<<(T_TOT + 64 + 255) / 256, 256, 0, stream>>>(blo, bhi, dirty);
    for (int r = 0; r < 4; ++r)
        k_relax<<<(T_TOT + RTILE - 1) / RTILE, 256, 0, stream>>>(thr32, hkpos, hkneg, blo, bhi);
    k_mark<<<NTILE, 1024, 0, stream>>>(blo, bhi, dirty);
    k_compact<<<NTILE, 1024, 0, stream>>>(blo, bhi, dirty, list, utot);
    k_chain<<<1, 256, 0, stream>>>(list, utot, chead);
    k_afix<<<(T_TOT + 255) / 256, 256, 0, stream>>>(list, utot, blo, hkd, afix);
    k_cresolve<<<(T_TOT + 255) / 256, 256, 0, stream>>>(list, chead, afix, thrd, hkd, utot, bits, blo, bhi);
    k_out<<<(T_TOT + TT1 - 1) / TT1, 256, 0, stream>>>(blo, spkk, hkd, xd, (float*)d_out);
}